// Round 1
// baseline (562.865 us; speedup 1.0000x reference)
//
#include <hip/hip_runtime.h>
#include <hip/hip_bf16.h>

// StratifiedRaysampler on MI355X.
// outputs: sample_points [N_RAYS,128,3] fp32  then sample_lengths [N_RAYS,128,1] fp32,
// concatenated flat in d_out.
// points[i,j,k] = (z_j / dir_z) * dir_k  -> z-component is exactly z_j.
// lengths[i,j]  = z_j.
// Pure write-BW bound: 512 MiB out, ~3 MiB in.

#ifndef N_PTS_C
#define N_PTS_C 128
#endif

constexpr int   kNPts   = 128;
constexpr int   kNRays  = 262144;
constexpr float kMinD   = 0.1f;
constexpr float kMaxD   = 6.0f;
constexpr float kStep   = (kMaxD - kMinD) / (float)(kNPts - 1);

// one thread = one ray x 4 consecutive points.
// threads per ray = 128/4 = 32; total threads = N_RAYS*32 = 8,388,608.
__global__ __launch_bounds__(256) void StratifiedRaysampler_kernel(
    const float* __restrict__ dirs,   // [N_RAYS,3]
    float* __restrict__ out)          // points then lengths
{
    const int t   = blockIdx.x * blockDim.x + threadIdx.x;
    const int ray = t >> 5;          // 32 threads per ray
    const int jg  = (t & 31) << 2;   // starting point index, multiple of 4

    // 32 lanes load the same 3 floats -> coalesces to a broadcast; tiny traffic.
    const float dx = dirs[ray * 3 + 0];
    const float dy = dirs[ray * 3 + 1];
    const float dz = dirs[ray * 3 + 2];

    const float inv = 1.0f / dz;     // exact fp32 div; once per thread
    const float rx  = dx * inv;
    const float ry  = dy * inv;

    float z[4];
#pragma unroll
    for (int q = 0; q < 4; ++q)
        z[q] = kMinD + (float)(jg + q) * kStep;

    // 12 point floats for j..j+3: (z*rx, z*ry, z) each
    float4 p0 = make_float4(z[0] * rx, z[0] * ry, z[0], z[1] * rx);
    float4 p1 = make_float4(z[1] * ry, z[1],      z[2] * rx, z[2] * ry);
    float4 p2 = make_float4(z[2],      z[3] * rx, z[3] * ry, z[3]);

    // base offset (ray*128 + jg)*3 floats; jg%4==0 -> byte offset multiple of 48 (16B aligned)
    float4* pdst = reinterpret_cast<float4*>(out + (size_t)(ray * kNPts + jg) * 3);
    pdst[0] = p0;
    pdst[1] = p1;
    pdst[2] = p2;

    // lengths region starts after all points
    float* lbase = out + (size_t)kNRays * kNPts * 3;
    float4* ldst = reinterpret_cast<float4*>(lbase + (size_t)ray * kNPts + jg);
    *ldst = make_float4(z[0], z[1], z[2], z[3]);
}

extern "C" void kernel_launch(void* const* d_in, const int* in_sizes, int n_in,
                              void* d_out, int out_size, void* d_ws, size_t ws_size,
                              hipStream_t stream) {
    // d_in[0] = origins (unused by the reference math), d_in[1] = directions
    const float* dirs = (const float*)d_in[1];
    float* out = (float*)d_out;

    const int total_threads = kNRays * (kNPts / 4);   // 8,388,608
    const int block = 256;
    const int grid  = total_threads / block;          // 32768

    StratifiedRaysampler_kernel<<<grid, block, 0, stream>>>(dirs, out);
}

// Round 2
// 545.704 us; speedup vs baseline: 1.0314x; 1.0314x over previous
//
#include <hip/hip_runtime.h>
#include <hip/hip_bf16.h>

// StratifiedRaysampler on MI355X — v2: fully lane-contiguous float4 stores.
//
// d_out layout (flat): sample_points [262144,128,3] fp32, then
// sample_lengths [262144,128,1] fp32.  Total 134,217,728 floats = 33,554,432
// float4s = 512 MiB.  Pure write-BW bound (~3 MiB of real input reads).
//
// v1 wrote points with a 48 B per-lane stride (3 float4/thread) -> each store
// instruction scattered over 48 partial cache lines.  v2 maps one thread per
// OUTPUT float4, so every wave store is one contiguous 1 KiB burst.
//
// points[i,j,:] = (z_j/dz)*(dx,dy,dz) -> (z_j*rx, z_j*ry, z_j) with
// rx=dx/dz, ry=dy/dz.  Per ray: 384 floats = 96 float4s (no ray straddle).
// float4 #r of a ray starts at float f0=4r; component phase e = f0%3 = r%3:
//   e==0: (x_j, y_j, z_j, x_{j+1})
//   e==1: (y_j, z_j, x_{j+1}, y_{j+1})
//   e==2: (z_j, x_{j+1}, y_{j+1}, z_{j+1})     with j = f0/3.
// lengths float4 = (z_k, z_{k+1}, z_{k+2}, z_{k+3}), k = (u%32)*4 — no loads.

constexpr int      kNPts    = 128;
constexpr int      kNRays   = 262144;
constexpr float    kMinD    = 0.1f;
constexpr float    kMaxD    = 6.0f;
constexpr float    kStep    = (kMaxD - kMinD) / (float)(kNPts - 1);
constexpr unsigned kPtsF4   = (unsigned)kNRays * kNPts * 3 / 4;  // 25,165,824
constexpr unsigned kTotalF4 = (unsigned)kNRays * kNPts * 4 / 4;  // 33,554,432

__global__ __launch_bounds__(256) void StratifiedRaysampler_kernel(
    const float* __restrict__ dirs,   // [N_RAYS,3]
    float4* __restrict__ out)         // points then lengths, as float4
{
    const unsigned u = blockIdx.x * 256u + threadIdx.x;

    if (u < kPtsF4) {
        // ---- points region ----
        const unsigned ray = u / 96u;            // magic-mul div
        const unsigned r   = u - ray * 96u;
        const unsigned f0  = r * 4u;
        const unsigned j   = f0 / 3u;            // const-div
        const unsigned e   = f0 - j * 3u;

        // neighbors share a ray -> these loads are L1-broadcast-cheap
        const float dx = dirs[ray * 3u + 0u];
        const float dy = dirs[ray * 3u + 1u];
        const float dz = dirs[ray * 3u + 2u];
        const float inv = 1.0f / dz;
        const float rx = dx * inv;
        const float ry = dy * inv;

        const float z0 = kMinD + (float)j * kStep;
        const float z1 = z0 + kStep;

        float4 v;
        if (e == 0u)      v = make_float4(z0 * rx, z0 * ry, z0,      z1 * rx);
        else if (e == 1u) v = make_float4(z0 * ry, z0,      z1 * rx, z1 * ry);
        else              v = make_float4(z0,      z1 * rx, z1 * ry, z1);
        out[u] = v;
    } else {
        // ---- lengths region: value depends only on point index ----
        const unsigned v4 = u - kPtsF4;
        const unsigned k  = (v4 & 31u) * 4u;     // 32 float4s per ray
        const float z0 = kMinD + (float)k * kStep;
        out[u] = make_float4(z0, z0 + kStep, z0 + 2.0f * kStep, z0 + 3.0f * kStep);
    }
}

extern "C" void kernel_launch(void* const* d_in, const int* in_sizes, int n_in,
                              void* d_out, int out_size, void* d_ws, size_t ws_size,
                              hipStream_t stream) {
    // d_in[0] = origins (unused by the reference math), d_in[1] = directions
    const float* dirs = (const float*)d_in[1];
    float4* out = (float4*)d_out;

    const unsigned block = 256;
    const unsigned grid  = kTotalF4 / block;     // 131,072 blocks
    StratifiedRaysampler_kernel<<<grid, block, 0, stream>>>(dirs, out);
}